// Round 4
// baseline (306.276 us; speedup 1.0000x reference)
//
#include <hip/hip_runtime.h>

// Problem constants (B=4, N=2048 fixed by the reference).
#define NN 2048
#define BB 4
#define PARAM_G 0.125f
#define VIRUS_DEATH 8e-5f

// Native clang vector types for __builtin_nontemporal_* (HIP_vector_type is
// rejected by the builtin).
typedef float nfloat2 __attribute__((ext_vector_type(2)));
typedef float nfloat4 __attribute__((ext_vector_type(4)));

// Workspace layout (floats):
//   [0,    8192)  colsum[b*N+j] = sum_i F_nm[b,i,j]  (atomics, zeroed)
//   [8192, 8196)  fai[b]  (atomics, zeroed)
//   [8196, 8200)  tau[b]
#define WS_FAI  8192
#define WS_TAU  8196
#define WS_ZERO_FLOATS 8200

// ---------------------------------------------------------------------------
// K1: column sums of mob (diag zeroed) + fai[b] + tau[b].
// grid (128 row-tiles of 16, 2 col-tiles of 1024, B) = 1024 blocks (4/CU).
// Full unroll -> 16 outstanding 16B loads per lane for latency hiding.
__global__ __launch_bounds__(256) void k_colsum(const float* __restrict__ mob,
                                                const float* __restrict__ SIR,
                                                float* ws) {
    int t  = threadIdx.x;
    int i0 = blockIdx.x * 16;
    int j  = blockIdx.y * 1024 + t * 4;
    int b  = blockIdx.z;
    const float* base = mob + ((size_t)b * NN + i0) * NN + j;
    float4 acc = make_float4(0.f, 0.f, 0.f, 0.f);
    #pragma unroll
    for (int r = 0; r < 16; ++r) {
        float4 v = *(const float4*)(base + (size_t)r * NN);
        unsigned d = (unsigned)((i0 + r) - j);      // diag: i == j+d, d in [0,4)
        if (d < 4u) ((float*)&v)[d] = 0.0f;
        acc.x += v.x; acc.y += v.y; acc.z += v.z; acc.w += v.w;
    }
    atomicAdd(&ws[b * NN + j + 0], acc.x);
    atomicAdd(&ws[b * NN + j + 1], acc.y);
    atomicAdd(&ws[b * NN + j + 2], acc.z);
    atomicAdd(&ws[b * NN + j + 3], acc.w);
    // fai[b] = sum of ALL F entries: wave-reduce, one atomic per wave.
    float s = acc.x + acc.y + acc.z + acc.w;
    for (int off = 32; off; off >>= 1) s += __shfl_down(s, off);
    if ((t & 63) == 0) atomicAdd(&ws[WS_FAI + b], s);
    // tau[b]: folded into the 4 blocks with (x,y)==(0,0). Uniform branch.
    if (blockIdx.x == 0 && blockIdx.y == 0) {
        float accT = 0.f;
        #pragma unroll
        for (int k = 0; k < 8; ++k) {
            int n = k * 256 + t;
            float4 sv = *(const float4*)(SIR + ((size_t)b * NN + n) * 4);
            accT += sv.x + sv.y + sv.z;
        }
        for (int off = 32; off; off >>= 1) accT += __shfl_down(accT, off);
        __shared__ float red[4];
        if ((t & 63) == 0) red[t >> 6] = accT;
        __syncthreads();
        if (t == 0) ws[WS_TAU + b] = red[0] + red[1] + red[2] + red[3];
    }
}

// ---------------------------------------------------------------------------
// K2: heavy pass + fused epilogue.
// Per row i: write arrive2[b,i,j,{0,1}] = {sps_m, P} (non-temporal, never
// re-read), accumulate rowdot_X = sum_j F*X via wave shuffle-reduce, then
// lane 0 computes the full per-node Ht_SIR / arrive1 epilogue for row i.
// 8 rows per block (2 per wave) amortizes the 24KB SIR->LDS staging.
__global__ __launch_bounds__(256) void k_main(const float* __restrict__ mob,
                                              const float* __restrict__ sps,
                                              const float* __restrict__ SIR,
                                              const float* __restrict__ param_b,
                                              const float* __restrict__ contact,
                                              const float* __restrict__ nb,
                                              const float* __restrict__ nd,
                                              const float* ws,
                                              float* __restrict__ out0,
                                              float* __restrict__ out1,
                                              float* __restrict__ out2) {
    __shared__ __align__(16) float sS[NN];
    __shared__ __align__(16) float sI[NN];
    __shared__ __align__(16) float sR[NN];
    int t = threadIdx.x;
    int b = blockIdx.y;
    for (int j = t; j < NN; j += 256) {
        float4 s = *(const float4*)(SIR + ((size_t)b * NN + j) * 4);
        sS[j] = s.x; sI[j] = s.y; sR[j] = s.z;
    }
    __syncthreads();

    int w = t >> 6, lane = t & 63;
    int i0 = blockIdx.x * 8;
    float m = ws[WS_FAI + b] / ws[WS_TAU + b];     // wave-uniform scalar
    #pragma unroll
    for (int k = 0; k < 2; ++k) {
        int i = i0 + w + 4 * k;
        float invc = 1.0f / ws[b * NN + i];        // wave-uniform -> broadcast
        size_t rowoff = ((size_t)b * NN + i) * NN;
        const float* mrow = mob + rowoff;
        const float* srow = sps + rowoff;
        float* orow = out2 + rowoff * 2;
        float aS = 0.f, aI = 0.f, aR = 0.f;
        #pragma unroll 4
        for (int iter = 0; iter < 16; ++iter) {
            int j2 = iter * 128 + lane * 2;        // this lane's column pair
            float2 mv = *(const float2*)(mrow + j2);
            nfloat2 sv = __builtin_nontemporal_load((const nfloat2*)(srow + j2));
            unsigned d = (unsigned)(i - j2);       // diag if d in {0,1}
            if (d == 0u)      { mv.x = 0.f; sv.x = 0.f; }
            else if (d == 1u) { mv.y = 0.f; sv.y = 0.f; }
            float2 xS = *(const float2*)&sS[j2];
            float2 xI = *(const float2*)&sI[j2];
            float2 xR = *(const float2*)&sR[j2];
            aS += mv.x * xS.x + mv.y * xS.y;
            aI += mv.x * xI.x + mv.y * xI.y;
            aR += mv.x * xR.x + mv.y * xR.y;
            nfloat4 o = { sv.x, mv.x * invc, sv.y, mv.y * invc };
            __builtin_nontemporal_store(o, (nfloat4*)(orow + (size_t)j2 * 2));
        }
        for (int off = 32; off; off >>= 1) {
            aS += __shfl_down(aS, off);
            aI += __shfl_down(aI, off);
            aR += __shfl_down(aR, off);
        }
        if (lane == 0) {                            // fused per-node epilogue
            int g = b * NN + i;
            float4 sir = *(const float4*)(SIR + (size_t)g * 4);
            float S = sir.x, I = sir.y, R = sir.z, Isum = sir.w;
            float pb = param_b[g], ct = contact[g];
            float birth = nb[i], death = nd[i];
            float pop   = S + I + R;
            float pbc   = pb * ct;
            float I_new = S / pop * pbc * I;
            float fS = m * aS * invc, fI = m * aI * invc, fR = m * aR * invc;
            float R_t    = R + PARAM_G * I - death * R - m * R + fR;
            float I_t    = I + I_new - death * I - PARAM_G * I - VIRUS_DEATH * I
                             - m * I + fI;
            float S_t    = S - I_new - death * S + birth * pop - m * S + fS;
            float Isum_t = Isum + I_new;
            float R0     = pbc / (death + PARAM_G + VIRUS_DEATH + m);
            float W      = pbc - death - PARAM_G - VIRUS_DEATH;
            float* o0 = out0 + (size_t)g * 6;
            *(float2*)(o0 + 0) = make_float2(R0, I_new);
            *(float2*)(o0 + 2) = make_float2(S_t, I_t);
            *(float2*)(o0 + 4) = make_float2(R_t, Isum_t);
            *(float4*)(out1 + (size_t)g * 4) = make_float4(W, m, I, pop);
        }
    }
}

// ---------------------------------------------------------------------------
extern "C" void kernel_launch(void* const* d_in, const int* in_sizes, int n_in,
                              void* d_out, int out_size, void* d_ws, size_t ws_size,
                              hipStream_t stream) {
    const float* param_b = (const float*)d_in[0];
    const float* contact = (const float*)d_in[1];
    const float* mob     = (const float*)d_in[2];
    const float* SIR     = (const float*)d_in[3];
    const float* sps     = (const float*)d_in[4];
    const float* nb      = (const float*)d_in[5];
    const float* nd      = (const float*)d_in[6];

    float* out  = (float*)d_out;
    float* out0 = out;                            // Ht_SIR   (B,N,6)
    float* out1 = out + (size_t)BB * NN * 6;      // arrive1  (B,N,4)
    float* out2 = out1 + (size_t)BB * NN * 4;     // arrive2  (B,N,N,2)
    float* ws   = (float*)d_ws;

    (void)hipMemsetAsync(ws, 0, (size_t)WS_ZERO_FLOATS * sizeof(float), stream);

    k_colsum<<<dim3(128, 2, BB), 256, 0, stream>>>(mob, SIR, ws);
    k_main  <<<dim3(NN / 8, BB), 256, 0, stream>>>(mob, sps, SIR, param_b, contact,
                                                   nb, nd, ws, out0, out1, out2);
}